// Round 13
// baseline (269.545 us; speedup 1.0000x reference)
//
#include <hip/hip_runtime.h>
#include <stdint.h>

#define MD 8192
#define ND 8192
#define KD 2048
#define KTH 15099494  // int(8192*2048*0.9)

#define NCOPY 16   // privatized LDS histogram copies
#define HSTR 257   // copy stride in words; 257 % 32 == 1 -> distinct banks per copy
#define NPART 8    // global histogram partials

typedef int v4i __attribute__((ext_vector_type(4)));

__device__ __forceinline__ void gload_lds16(const void* g, void* l) {
  __builtin_amdgcn_global_load_lds(
      (const __attribute__((address_space(1))) uint32_t*)g,
      (__attribute__((address_space(3))) uint32_t*)l, 16, 0, 0);
}

// ---------------- absmax: both tensors, ONE global atomic per block ----------------
__global__ void absmax2_kernel(const float* __restrict__ x1, const float* __restrict__ x2,
                               unsigned int* sbits) {
  __shared__ float wred[4];
  const float4* p = (const float4*)(blockIdx.y ? x2 : x1);
  const int n4 = MD * KD / 4;
  int tid = blockIdx.x * blockDim.x + threadIdx.x;
  int stride = gridDim.x * blockDim.x;
  float m = 0.f;
  for (int i = tid; i < n4; i += stride) {
    float4 v = p[i];
    m = fmaxf(m, fmaxf(fmaxf(fabsf(v.x), fabsf(v.y)), fmaxf(fabsf(v.z), fabsf(v.w))));
  }
  #pragma unroll
  for (int off = 32; off; off >>= 1) m = fmaxf(m, __shfl_down(m, off, 64));
  if ((threadIdx.x & 63) == 0) wred[threadIdx.x >> 6] = m;
  __syncthreads();
  if (threadIdx.x == 0) {
    float bm = fmaxf(fmaxf(wred[0], wred[1]), fmaxf(wred[2], wred[3]));
    atomicMax(&sbits[blockIdx.y], __float_as_uint(bm));
  }
}

// ---------------- quantize x1 (row-major keep) + privatized histogram ----------------
__global__ void quant_hist_kernel(const float* __restrict__ x, int8_t* __restrict__ q,
                                  int n4, const unsigned int* sbits, unsigned int* hist) {
  __shared__ unsigned int h[NCOPY * HSTR];
  for (int i = threadIdx.x; i < NCOPY * HSTR; i += blockDim.x) h[i] = 0;
  __syncthreads();
  unsigned int* hc = h + (threadIdx.x & (NCOPY - 1)) * HSTR;
  float s = __uint_as_float(*sbits);
  int tid = blockIdx.x * blockDim.x + threadIdx.x;
  int stride = gridDim.x * blockDim.x;
  const float4* p = (const float4*)x;
  uint32_t* qo = (uint32_t*)q;
  for (int i = tid; i < n4; i += stride) {
    float4 v = p[i];
    int q0 = (int)rintf(v.x / s * 127.0f);   // keep (x/s)*127 order: matches np bit-exactly
    int q1 = (int)rintf(v.y / s * 127.0f);
    int q2 = (int)rintf(v.z / s * 127.0f);
    int q3 = (int)rintf(v.w / s * 127.0f);
    atomicAdd(&hc[q0 + 127], 1u);
    atomicAdd(&hc[q1 + 127], 1u);
    atomicAdd(&hc[q2 + 127], 1u);
    atomicAdd(&hc[q3 + 127], 1u);
    uint32_t packed = (uint32_t)(uint8_t)(int8_t)q0 |
                      ((uint32_t)(uint8_t)(int8_t)q1 << 8) |
                      ((uint32_t)(uint8_t)(int8_t)q2 << 16) |
                      ((uint32_t)(uint8_t)(int8_t)q3 << 24);
    qo[i] = packed;
  }
  __syncthreads();
  {
    int b = threadIdx.x;
    unsigned int sum = 0;
    #pragma unroll
    for (int c = 0; c < NCOPY; ++c) sum += h[c * HSTR + b];
    if (sum) atomicAdd(&hist[(blockIdx.x & (NPART - 1)) * 256 + b], sum);
  }
}

// ---------------- quantize x2 transposed ([K][N] -> q2t[N][K]) + privatized histogram ----
#define TSTR 17
__global__ void transq_kernel(const float* __restrict__ x, int8_t* __restrict__ qt,
                              const unsigned int* sbits, unsigned int* hist) {
  __shared__ unsigned int tile2[64 * TSTR];
  __shared__ unsigned int h[NCOPY * HSTR];
  for (int i = threadIdx.x; i < NCOPY * HSTR; i += blockDim.x) h[i] = 0;
  __syncthreads();
  unsigned int* hc = h + (threadIdx.x & (NCOPY - 1)) * HSTR;
  float s = __uint_as_float(*sbits);
  int n0 = blockIdx.x * 64, k0 = blockIdx.y * 64;
  int t = threadIdx.x;
  int nq = t & 15, kq = t >> 4;
  unsigned int pk[4] = {0, 0, 0, 0};
  #pragma unroll
  for (int j = 0; j < 4; ++j) {
    float4 v = *(const float4*)(x + (size_t)(k0 + kq * 4 + j) * ND + n0 + nq * 4);
    int q0 = (int)rintf(v.x / s * 127.0f);
    int q1 = (int)rintf(v.y / s * 127.0f);
    int q2 = (int)rintf(v.z / s * 127.0f);
    int q3 = (int)rintf(v.w / s * 127.0f);
    atomicAdd(&hc[q0 + 127], 1u);
    atomicAdd(&hc[q1 + 127], 1u);
    atomicAdd(&hc[q2 + 127], 1u);
    atomicAdd(&hc[q3 + 127], 1u);
    pk[0] |= ((unsigned int)(uint8_t)(int8_t)q0) << (8 * j);
    pk[1] |= ((unsigned int)(uint8_t)(int8_t)q1) << (8 * j);
    pk[2] |= ((unsigned int)(uint8_t)(int8_t)q2) << (8 * j);
    pk[3] |= ((unsigned int)(uint8_t)(int8_t)q3) << (8 * j);
  }
  #pragma unroll
  for (int i = 0; i < 4; ++i) tile2[(nq * 4 + i) * TSTR + kq] = pk[i];
  __syncthreads();
  {
    int n = t >> 2, c = t & 3;
    uint4 val;
    val.x = tile2[n * TSTR + c * 4 + 0];
    val.y = tile2[n * TSTR + c * 4 + 1];
    val.z = tile2[n * TSTR + c * 4 + 2];
    val.w = tile2[n * TSTR + c * 4 + 3];
    *(uint4*)(qt + (size_t)(n0 + n) * KD + k0 + c * 16) = val;
  }
  __syncthreads();
  {
    int b = threadIdx.x;
    unsigned int sum = 0;
    #pragma unroll
    for (int c = 0; c < NCOPY; ++c) sum += h[c * HSTR + b];
    if (sum) atomicAdd(&hist[((blockIdx.x + blockIdx.y) & (NPART - 1)) * 256 + b], sum);
  }
}

// ---------------- kth-value: sum partials, prefix scan, pick crossing ----------------
__global__ void finalize_kernel(const unsigned int* __restrict__ hist1,
                                const unsigned int* __restrict__ hist2,
                                float* __restrict__ out_k) {
  __shared__ unsigned int c[256];
  __shared__ int result;
  int t = threadIdx.x;
  const unsigned int* h = (blockIdx.x == 0) ? hist1 : hist2;
  unsigned int sum = 0;
  #pragma unroll
  for (int p = 0; p < NPART; ++p) sum += h[p * 256 + t];
  c[t] = sum;
  if (t == 0) result = 127;
  __syncthreads();
  #pragma unroll
  for (int off = 1; off < 256; off <<= 1) {
    unsigned int add = (t >= off) ? c[t - off] : 0u;
    __syncthreads();
    c[t] += add;
    __syncthreads();
  }
  unsigned int prev = (t == 0) ? 0u : c[t - 1];
  if (c[t] >= (unsigned int)KTH && prev < (unsigned int)KTH) result = t - 127;
  __syncthreads();
  if (t == 0) out_k[blockIdx.x] = (float)result;
}

// ---------------- i8 GEMM: round-10 best + convoy desync via K-loop rotation --------
// 128x128 tile, BK=128, single-buffered 32KB LDS, 4 waves 2x2, __syncthreads,
// 5-blocks/CU hint (R10's best: 155-158us). ONLY change: each block starts its
// K-loop at kt0 = (bcol&3)*4 and wraps (integer accumulation is order-exact).
// Same-bcol 8-block L2 groups stay phase-aligned (B-panel sharing intact);
// different-bcol convoys stage/compute at 4 staggered phases so one convoy's
// staging drain overlaps another's MFMA burst (breaks convoy phase-locking,
// the hypothesized cause of 40% util at 3.2x oversubscription).
__global__ __launch_bounds__(256, 5) void gemm_i8_kernel(
    const int8_t* __restrict__ qa, const int8_t* __restrict__ qb,
    float* __restrict__ out, const unsigned int* __restrict__ sbits) {
  __shared__ __align__(16) int8_t Asm[128 * 128];
  __shared__ __align__(16) int8_t Bsm[128 * 128];

  // XCD supergroup (bijective, 4096 = 8*8*64): ~4MB working set per XCD ~= L2
  int bid = blockIdx.x;
  int xcd = bid & 7;
  int local = bid >> 3;               // 0..511
  int brow = xcd * 8 + (local & 7);   // 0..63
  int bcol = local >> 3;              // 0..63

  int t = threadIdx.x;
  int lane = t & 63;
  int w = t >> 6;
  int wr = (w >> 1) * 64, wc = (w & 1) * 64;

  v4i acc[4][4] = {};

  const int8_t* ga = qa + (size_t)brow * 128 * KD;
  const int8_t* gb = qb + (size_t)bcol * 128 * KD;

  int srow = t >> 3;     // 0..31 (row within 32-row staging slab)
  int schunk = t & 7;    // swizzled 16B-chunk slot in LDS row

  int kt0 = (bcol & 3) * 4;  // 4-group phase desync, wraps mod 16

  for (int ktt = 0; ktt < KD / 128; ++ktt) {
    int kt = (ktt + kt0) & 15;
    int kbase = kt * 128;
    #pragma unroll
    for (int i = 0; i < 4; ++i) {
      int row = i * 32 + srow;
      int gchunk = schunk ^ (row & 7);  // pre-swizzled global source
      gload_lds16(ga + (size_t)row * KD + kbase + gchunk * 16, Asm + i * 4096 + t * 16);
    }
    #pragma unroll
    for (int i = 0; i < 4; ++i) {
      int row = i * 32 + srow;
      int gchunk = schunk ^ (row & 7);
      gload_lds16(gb + (size_t)row * KD + kbase + gchunk * 16, Bsm + i * 4096 + t * 16);
    }
    __syncthreads();
    #pragma unroll
    for (int kh = 0; kh < 2; ++kh) {
      v4i aF[4], bF[4];
      #pragma unroll
      for (int m = 0; m < 4; ++m) {
        int row = wr + m * 16 + (lane & 15);
        int chunk = (kh * 4 + (lane >> 4)) ^ (row & 7);
        aF[m] = *(const v4i*)(Asm + row * 128 + chunk * 16);
      }
      #pragma unroll
      for (int n = 0; n < 4; ++n) {
        int row = wc + n * 16 + (lane & 15);
        int chunk = (kh * 4 + (lane >> 4)) ^ (row & 7);
        bF[n] = *(const v4i*)(Bsm + row * 128 + chunk * 16);
      }
      #pragma unroll
      for (int m = 0; m < 4; ++m)
        #pragma unroll
        for (int n = 0; n < 4; ++n)
          acc[m][n] = __builtin_amdgcn_mfma_i32_16x16x64_i8(aF[m], bF[n], acc[m][n], 0, 0, 0);
    }
    __syncthreads();
  }

  float s1 = __uint_as_float(sbits[0]);
  float s2 = __uint_as_float(sbits[1]);
  float scale = s1 * s2 / (127.0f * 127.0f);
  int orow = brow * 128 + wr + ((lane >> 4) * 4);
  int ocol = bcol * 128 + wc + (lane & 15);
  #pragma unroll
  for (int m = 0; m < 4; ++m)
    #pragma unroll
    for (int n = 0; n < 4; ++n)
      #pragma unroll
      for (int r = 0; r < 4; ++r)
        out[(size_t)(orow + m * 16 + r) * ND + (ocol + n * 16)] = (float)acc[m][n][r] * scale;
}

extern "C" void kernel_launch(void* const* d_in, const int* in_sizes, int n_in,
                              void* d_out, int out_size, void* d_ws, size_t ws_size,
                              hipStream_t stream) {
  const float* x1 = (const float*)d_in[0];
  const float* x2 = (const float*)d_in[1];
  float* out = (float*)d_out;
  uint8_t* ws = (uint8_t*)d_ws;

  unsigned int* sbits = (unsigned int*)ws;
  unsigned int* hist1 = (unsigned int*)(ws + 256);
  unsigned int* hist2 = (unsigned int*)(ws + 256 + 8192);
  int8_t* q1  = (int8_t*)(ws + 32768);
  int8_t* q2t = q1 + (size_t)MD * KD;

  const int n4_1 = MD * KD / 4;
  const int n4_2 = KD * ND / 4;

  hipMemsetAsync(ws, 0, 32768, stream);
  absmax2_kernel<<<dim3(512, 2), 256, 0, stream>>>(x1, x2, sbits);
  quant_hist_kernel<<<1024, 256, 0, stream>>>(x1, q1, n4_1, sbits + 0, hist1);
  transq_kernel<<<dim3(ND / 64, KD / 64), 256, 0, stream>>>(x2, q2t, sbits + 1, hist2);
  finalize_kernel<<<2, 256, 0, stream>>>(hist1, hist2, out + (size_t)MD * ND);
  gemm_i8_kernel<<<4096, 256, 0, stream>>>(q1, q2t, out, sbits);
}

// Round 14
// 217.785 us; speedup vs baseline: 1.2377x; 1.2377x over previous
//
#include <hip/hip_runtime.h>
#include <stdint.h>

#define MD 8192
#define ND 8192
#define KD 2048
#define KTH 15099494  // int(8192*2048*0.9)

#define NCOPY 16   // privatized LDS histogram copies
#define HSTR 257   // copy stride in words; 257 % 32 == 1 -> distinct banks per copy
#define NPART 8    // global histogram partials

typedef int v4i __attribute__((ext_vector_type(4)));

__device__ __forceinline__ void gload_lds16(const void* g, void* l) {
  __builtin_amdgcn_global_load_lds(
      (const __attribute__((address_space(1))) uint32_t*)g,
      (__attribute__((address_space(3))) uint32_t*)l, 16, 0, 0);
}

// ---------------- absmax: both tensors, ONE global atomic per block ----------------
__global__ void absmax2_kernel(const float* __restrict__ x1, const float* __restrict__ x2,
                               unsigned int* sbits) {
  __shared__ float wred[4];
  const float4* p = (const float4*)(blockIdx.y ? x2 : x1);
  const int n4 = MD * KD / 4;
  int tid = blockIdx.x * blockDim.x + threadIdx.x;
  int stride = gridDim.x * blockDim.x;
  float m = 0.f;
  for (int i = tid; i < n4; i += stride) {
    float4 v = p[i];
    m = fmaxf(m, fmaxf(fmaxf(fabsf(v.x), fabsf(v.y)), fmaxf(fabsf(v.z), fabsf(v.w))));
  }
  #pragma unroll
  for (int off = 32; off; off >>= 1) m = fmaxf(m, __shfl_down(m, off, 64));
  if ((threadIdx.x & 63) == 0) wred[threadIdx.x >> 6] = m;
  __syncthreads();
  if (threadIdx.x == 0) {
    float bm = fmaxf(fmaxf(wred[0], wred[1]), fmaxf(wred[2], wred[3]));
    atomicMax(&sbits[blockIdx.y], __float_as_uint(bm));
  }
}

// ---------------- quantize x1 (row-major keep) + privatized histogram ----------------
__global__ void quant_hist_kernel(const float* __restrict__ x, int8_t* __restrict__ q,
                                  int n4, const unsigned int* sbits, unsigned int* hist) {
  __shared__ unsigned int h[NCOPY * HSTR];
  for (int i = threadIdx.x; i < NCOPY * HSTR; i += blockDim.x) h[i] = 0;
  __syncthreads();
  unsigned int* hc = h + (threadIdx.x & (NCOPY - 1)) * HSTR;
  float s = __uint_as_float(*sbits);
  int tid = blockIdx.x * blockDim.x + threadIdx.x;
  int stride = gridDim.x * blockDim.x;
  const float4* p = (const float4*)x;
  uint32_t* qo = (uint32_t*)q;
  for (int i = tid; i < n4; i += stride) {
    float4 v = p[i];
    int q0 = (int)rintf(v.x / s * 127.0f);   // keep (x/s)*127 order: matches np bit-exactly
    int q1 = (int)rintf(v.y / s * 127.0f);
    int q2 = (int)rintf(v.z / s * 127.0f);
    int q3 = (int)rintf(v.w / s * 127.0f);
    atomicAdd(&hc[q0 + 127], 1u);
    atomicAdd(&hc[q1 + 127], 1u);
    atomicAdd(&hc[q2 + 127], 1u);
    atomicAdd(&hc[q3 + 127], 1u);
    uint32_t packed = (uint32_t)(uint8_t)(int8_t)q0 |
                      ((uint32_t)(uint8_t)(int8_t)q1 << 8) |
                      ((uint32_t)(uint8_t)(int8_t)q2 << 16) |
                      ((uint32_t)(uint8_t)(int8_t)q3 << 24);
    qo[i] = packed;
  }
  __syncthreads();
  {
    int b = threadIdx.x;
    unsigned int sum = 0;
    #pragma unroll
    for (int c = 0; c < NCOPY; ++c) sum += h[c * HSTR + b];
    if (sum) atomicAdd(&hist[(blockIdx.x & (NPART - 1)) * 256 + b], sum);
  }
}

// ---------------- quantize x2 transposed ([K][N] -> q2t[N][K]) + privatized histogram ----
#define TSTR 17
__global__ void transq_kernel(const float* __restrict__ x, int8_t* __restrict__ qt,
                              const unsigned int* sbits, unsigned int* hist) {
  __shared__ unsigned int tile2[64 * TSTR];
  __shared__ unsigned int h[NCOPY * HSTR];
  for (int i = threadIdx.x; i < NCOPY * HSTR; i += blockDim.x) h[i] = 0;
  __syncthreads();
  unsigned int* hc = h + (threadIdx.x & (NCOPY - 1)) * HSTR;
  float s = __uint_as_float(*sbits);
  int n0 = blockIdx.x * 64, k0 = blockIdx.y * 64;
  int t = threadIdx.x;
  int nq = t & 15, kq = t >> 4;
  unsigned int pk[4] = {0, 0, 0, 0};
  #pragma unroll
  for (int j = 0; j < 4; ++j) {
    float4 v = *(const float4*)(x + (size_t)(k0 + kq * 4 + j) * ND + n0 + nq * 4);
    int q0 = (int)rintf(v.x / s * 127.0f);
    int q1 = (int)rintf(v.y / s * 127.0f);
    int q2 = (int)rintf(v.z / s * 127.0f);
    int q3 = (int)rintf(v.w / s * 127.0f);
    atomicAdd(&hc[q0 + 127], 1u);
    atomicAdd(&hc[q1 + 127], 1u);
    atomicAdd(&hc[q2 + 127], 1u);
    atomicAdd(&hc[q3 + 127], 1u);
    pk[0] |= ((unsigned int)(uint8_t)(int8_t)q0) << (8 * j);
    pk[1] |= ((unsigned int)(uint8_t)(int8_t)q1) << (8 * j);
    pk[2] |= ((unsigned int)(uint8_t)(int8_t)q2) << (8 * j);
    pk[3] |= ((unsigned int)(uint8_t)(int8_t)q3) << (8 * j);
  }
  #pragma unroll
  for (int i = 0; i < 4; ++i) tile2[(nq * 4 + i) * TSTR + kq] = pk[i];
  __syncthreads();
  {
    int n = t >> 2, c = t & 3;
    uint4 val;
    val.x = tile2[n * TSTR + c * 4 + 0];
    val.y = tile2[n * TSTR + c * 4 + 1];
    val.z = tile2[n * TSTR + c * 4 + 2];
    val.w = tile2[n * TSTR + c * 4 + 3];
    *(uint4*)(qt + (size_t)(n0 + n) * KD + k0 + c * 16) = val;
  }
  __syncthreads();
  {
    int b = threadIdx.x;
    unsigned int sum = 0;
    #pragma unroll
    for (int c = 0; c < NCOPY; ++c) sum += h[c * HSTR + b];
    if (sum) atomicAdd(&hist[((blockIdx.x + blockIdx.y) & (NPART - 1)) * 256 + b], sum);
  }
}

// ---------------- kth-value: sum partials, prefix scan, pick crossing ----------------
__global__ void finalize_kernel(const unsigned int* __restrict__ hist1,
                                const unsigned int* __restrict__ hist2,
                                float* __restrict__ out_k) {
  __shared__ unsigned int c[256];
  __shared__ int result;
  int t = threadIdx.x;
  const unsigned int* h = (blockIdx.x == 0) ? hist1 : hist2;
  unsigned int sum = 0;
  #pragma unroll
  for (int p = 0; p < NPART; ++p) sum += h[p * 256 + t];
  c[t] = sum;
  if (t == 0) result = 127;
  __syncthreads();
  #pragma unroll
  for (int off = 1; off < 256; off <<= 1) {
    unsigned int add = (t >= off) ? c[t - off] : 0u;
    __syncthreads();
    c[t] += add;
    __syncthreads();
  }
  unsigned int prev = (t == 0) ? 0u : c[t - 1];
  if (c[t] >= (unsigned int)KTH && prev < (unsigned int)KTH) result = t - 127;
  __syncthreads();
  if (t == 0) out_k[blockIdx.x] = (float)result;
}

// ---------------- i8 GEMM: best measured configuration (round 10) ----------------
// 128x128 tile, BK=128, single-buffered 32KB LDS, 4 waves 2x2, __syncthreads,
// XCD supergroup, 0-conflict row&7 chunk swizzle, 5-blocks/CU hint.
// 13-structure search result: this simple form is the plateau (~156us, 44% of
// the 3944 TOPS i8 µbench ceiling); all deeper pipelines/geometries were null.
__global__ __launch_bounds__(256, 5) void gemm_i8_kernel(
    const int8_t* __restrict__ qa, const int8_t* __restrict__ qb,
    float* __restrict__ out, const unsigned int* __restrict__ sbits) {
  __shared__ __align__(16) int8_t Asm[128 * 128];
  __shared__ __align__(16) int8_t Bsm[128 * 128];

  // XCD supergroup (bijective, 4096 = 8*8*64): ~4MB working set per XCD ~= L2
  int bid = blockIdx.x;
  int xcd = bid & 7;
  int local = bid >> 3;               // 0..511
  int brow = xcd * 8 + (local & 7);   // 0..63
  int bcol = local >> 3;              // 0..63

  int t = threadIdx.x;
  int lane = t & 63;
  int w = t >> 6;
  int wr = (w >> 1) * 64, wc = (w & 1) * 64;

  v4i acc[4][4] = {};

  const int8_t* ga = qa + (size_t)brow * 128 * KD;
  const int8_t* gb = qb + (size_t)bcol * 128 * KD;

  int srow = t >> 3;     // 0..31 (row within 32-row staging slab)
  int schunk = t & 7;    // swizzled 16B-chunk slot in LDS row

  for (int kt = 0; kt < KD / 128; ++kt) {
    int kbase = kt * 128;
    #pragma unroll
    for (int i = 0; i < 4; ++i) {
      int row = i * 32 + srow;
      int gchunk = schunk ^ (row & 7);  // pre-swizzled global source
      gload_lds16(ga + (size_t)row * KD + kbase + gchunk * 16, Asm + i * 4096 + t * 16);
    }
    #pragma unroll
    for (int i = 0; i < 4; ++i) {
      int row = i * 32 + srow;
      int gchunk = schunk ^ (row & 7);
      gload_lds16(gb + (size_t)row * KD + kbase + gchunk * 16, Bsm + i * 4096 + t * 16);
    }
    __syncthreads();
    #pragma unroll
    for (int kh = 0; kh < 2; ++kh) {
      v4i aF[4], bF[4];
      #pragma unroll
      for (int m = 0; m < 4; ++m) {
        int row = wr + m * 16 + (lane & 15);
        int chunk = (kh * 4 + (lane >> 4)) ^ (row & 7);
        aF[m] = *(const v4i*)(Asm + row * 128 + chunk * 16);
      }
      #pragma unroll
      for (int n = 0; n < 4; ++n) {
        int row = wc + n * 16 + (lane & 15);
        int chunk = (kh * 4 + (lane >> 4)) ^ (row & 7);
        bF[n] = *(const v4i*)(Bsm + row * 128 + chunk * 16);
      }
      #pragma unroll
      for (int m = 0; m < 4; ++m)
        #pragma unroll
        for (int n = 0; n < 4; ++n)
          acc[m][n] = __builtin_amdgcn_mfma_i32_16x16x64_i8(aF[m], bF[n], acc[m][n], 0, 0, 0);
    }
    __syncthreads();
  }

  float s1 = __uint_as_float(sbits[0]);
  float s2 = __uint_as_float(sbits[1]);
  float scale = s1 * s2 / (127.0f * 127.0f);
  int orow = brow * 128 + wr + ((lane >> 4) * 4);
  int ocol = bcol * 128 + wc + (lane & 15);
  #pragma unroll
  for (int m = 0; m < 4; ++m)
    #pragma unroll
    for (int n = 0; n < 4; ++n)
      #pragma unroll
      for (int r = 0; r < 4; ++r)
        out[(size_t)(orow + m * 16 + r) * ND + (ocol + n * 16)] = (float)acc[m][n][r] * scale;
}

extern "C" void kernel_launch(void* const* d_in, const int* in_sizes, int n_in,
                              void* d_out, int out_size, void* d_ws, size_t ws_size,
                              hipStream_t stream) {
  const float* x1 = (const float*)d_in[0];
  const float* x2 = (const float*)d_in[1];
  float* out = (float*)d_out;
  uint8_t* ws = (uint8_t*)d_ws;

  unsigned int* sbits = (unsigned int*)ws;
  unsigned int* hist1 = (unsigned int*)(ws + 256);
  unsigned int* hist2 = (unsigned int*)(ws + 256 + 8192);
  int8_t* q1  = (int8_t*)(ws + 32768);
  int8_t* q2t = q1 + (size_t)MD * KD;

  const int n4_1 = MD * KD / 4;
  const int n4_2 = KD * ND / 4;

  hipMemsetAsync(ws, 0, 32768, stream);
  absmax2_kernel<<<dim3(512, 2), 256, 0, stream>>>(x1, x2, sbits);
  quant_hist_kernel<<<1024, 256, 0, stream>>>(x1, q1, n4_1, sbits + 0, hist1);
  transq_kernel<<<dim3(ND / 64, KD / 64), 256, 0, stream>>>(x2, q2t, sbits + 1, hist2);
  finalize_kernel<<<2, 256, 0, stream>>>(hist1, hist2, out + (size_t)MD * ND);
  gemm_i8_kernel<<<4096, 256, 0, stream>>>(q1, q2t, out, sbits);
}